// Round 7
// baseline (329.577 us; speedup 1.0000x reference)
//
#include <hip/hip_runtime.h>
#include <hip/hip_bf16.h>
#include <stdint.h>

#define T_DIM 2048
#define C_DIM 1024
#define H_DIM 16
#define D_HEAD 64
#define N_QKV 3072
#define CQ 0.18033688011112042f   // log2(e)/8

typedef __bf16 bf16;
typedef __bf16 bf16x8 __attribute__((ext_vector_type(8)));
typedef __bf16 bf16x4 __attribute__((ext_vector_type(4)));
typedef __bf16 bf16x2 __attribute__((ext_vector_type(2)));
typedef float f32x4 __attribute__((ext_vector_type(4)));
typedef short s16x4 __attribute__((ext_vector_type(4)));

__device__ __forceinline__ void lds_load16(const void* g, void* l) {
    __builtin_amdgcn_global_load_lds(
        (const __attribute__((address_space(1))) void*)g,
        (__attribute__((address_space(3))) void*)l, 16, 0, 0);
}

__device__ __forceinline__ f32x4 mfma16(bf16x4 a, bf16x4 b, f32x4 c) {
#if __has_builtin(__builtin_amdgcn_mfma_f32_16x16x16_bf16)
    return __builtin_amdgcn_mfma_f32_16x16x16_bf16(a, b, c, 0, 0, 0);
#elif __has_builtin(__builtin_amdgcn_mfma_f32_16x16x16bf16_1k)
    union { bf16x4 v; s16x4 s; } ua, ub;
    ua.v = a; ub.v = b;
    return __builtin_amdgcn_mfma_f32_16x16x16bf16_1k(ua.s, ub.s, c, 0, 0, 0);
#else
    asm volatile("v_mfma_f32_16x16x16_bf16 %0, %1, %2, %0"
                 : "+v"(c) : "v"(a), "v"(b));
    return c;
#endif
}

// ---- merged prep: blocks 0..1023 cast x; blocks 1024..5119 transpose both weights ----
__global__ void prep_kernel(const float* __restrict__ x, bf16* __restrict__ xb,
                            const float* __restrict__ Wq, bf16* __restrict__ WqT,
                            const float* __restrict__ Wp, bf16* __restrict__ WpT) {
    __shared__ float tile[32][33];
    int bid = blockIdx.x;
    int t = threadIdx.x;
    if (bid < 1024) {
        int i = (bid * 256 + t) * 8;
        float4 a = *(const float4*)(x + i);
        float4 b = *(const float4*)(x + i + 4);
        bf16x8 o;
        o[0] = (bf16)a.x; o[1] = (bf16)a.y; o[2] = (bf16)a.z; o[3] = (bf16)a.w;
        o[4] = (bf16)b.x; o[5] = (bf16)b.y; o[6] = (bf16)b.z; o[7] = (bf16)b.w;
        *(bf16x8*)(xb + i) = o;
        return;
    }
    bid -= 1024;
    const float* in; bf16* out; int N, nb, kb;
    if (bid < 3072) { in = Wq; out = WqT; N = N_QKV; nb = (bid % 96) * 32; kb = (bid / 96) * 32; }
    else { bid -= 3072; in = Wp; out = WpT; N = C_DIM; nb = (bid % 32) * 32; kb = (bid / 32) * 32; }
    int r = t >> 3, c4 = (t & 7) * 4;
    float4 v = *(const float4*)(in + (size_t)(kb + r) * N + nb + c4);
    tile[r][c4 + 0] = v.x; tile[r][c4 + 1] = v.y;
    tile[r][c4 + 2] = v.z; tile[r][c4 + 3] = v.w;
    __syncthreads();
    bf16x4 ov;
    ov[0] = (bf16)tile[c4 + 0][r]; ov[1] = (bf16)tile[c4 + 1][r];
    ov[2] = (bf16)tile[c4 + 2][r]; ov[3] = (bf16)tile[c4 + 3][r];
    *(bf16x4*)(out + (size_t)(nb + r) * C_DIM + kb + c4) = ov;
}

// ---------------- QKV GEMM 128x128, BK=64, 2-phase DMA pipeline, XCD-swizzled ----------------
#define QKV_STAGE(BUF, K0) do {                                                      \
    lds_load16(ga + (K0),                            &As[BUF][0][(w * 16) * 32]);    \
    lds_load16(ga + (K0) + 32,                       &As[BUF][1][(w * 16) * 32]);    \
    lds_load16(ga + (size_t)64 * C_DIM + (K0),       &As[BUF][0][(64 + w * 16) * 32]); \
    lds_load16(ga + (size_t)64 * C_DIM + (K0) + 32,  &As[BUF][1][(64 + w * 16) * 32]); \
    lds_load16(gb + (K0),                            &Bs[BUF][0][(w * 16) * 32]);    \
    lds_load16(gb + (K0) + 32,                       &Bs[BUF][1][(w * 16) * 32]);    \
    lds_load16(gb + (size_t)64 * C_DIM + (K0),       &Bs[BUF][0][(64 + w * 16) * 32]); \
    lds_load16(gb + (size_t)64 * C_DIM + (K0) + 32,  &Bs[BUF][1][(64 + w * 16) * 32]); \
} while (0)

#define QKV_COMPUTE(BUF) do {                                                \
    _Pragma("unroll")                                                        \
    for (int p = 0; p < 2; ++p) {                                            \
        bf16x8 af[4], bfr[4];                                                \
        _Pragma("unroll")                                                    \
        for (int mi = 0; mi < 4; ++mi) af[mi]  = *(const bf16x8*)&As[BUF][p][(wm + mi * 16 + lo16) * 32 + quad * 8]; \
        _Pragma("unroll")                                                    \
        for (int ni = 0; ni < 4; ++ni) bfr[ni] = *(const bf16x8*)&Bs[BUF][p][(wn + ni * 16 + lo16) * 32 + quad * 8]; \
        _Pragma("unroll")                                                    \
        for (int mi = 0; mi < 4; ++mi)                                       \
            _Pragma("unroll")                                                \
            for (int ni = 0; ni < 4; ++ni)                                   \
                acc[mi][ni] = __builtin_amdgcn_mfma_f32_16x16x32_bf16(af[mi], bfr[ni], acc[mi][ni], 0, 0, 0); \
    }                                                                        \
} while (0)

#define WAIT_AND_BARRIER() do {                                              \
    asm volatile("s_waitcnt vmcnt(0)" ::: "memory");                         \
    __builtin_amdgcn_s_barrier();                                            \
} while (0)

__global__ __launch_bounds__(256, 2) void qkv_gemm_kernel(
    const bf16* __restrict__ A, const bf16* __restrict__ Bt,
    const float* __restrict__ bias, bf16* __restrict__ qkv)
{
    __shared__ __align__(16) bf16 As[2][2][128 * 32];
    __shared__ __align__(16) bf16 Bs[2][2][128 * 32];
    const int bid = blockIdx.x;
    const int xcd = bid & 7, slot = bid >> 3;            // slot 0..47
    const int rowBase = (slot / 3) * 128;                // 16 row-blocks
    const int colBase = (xcd * 3 + (slot % 3)) * 128;    // 24 col-blocks
    const int tid = threadIdx.x, lane = tid & 63, w = tid >> 6;
    const int lo16 = lane & 15, quad = lane >> 4;
    const int wm = (w & 1) * 64, wn = (w >> 1) * 64;

    const bf16* ga = A  + (size_t)(rowBase + w * 16 + (lane >> 2)) * C_DIM + (lane & 3) * 8;
    const bf16* gb = Bt + (size_t)(colBase + w * 16 + (lane >> 2)) * C_DIM + (lane & 3) * 8;

    f32x4 acc[4][4] = {};

    QKV_STAGE(0, 0);
    WAIT_AND_BARRIER();

    for (int k0 = 0; k0 < C_DIM; k0 += 128) {
        QKV_STAGE(1, k0 + 64);
        QKV_COMPUTE(0);
        WAIT_AND_BARRIER();
        if (k0 + 128 < C_DIM) QKV_STAGE(0, k0 + 128);
        QKV_COMPUTE(1);
        WAIT_AND_BARRIER();
    }

    const float scale = (colBase < C_DIM) ? CQ : 1.0f;   // Q region prescale (128 | 1024)
    #pragma unroll
    for (int ni = 0; ni < 4; ++ni) {
        int col = colBase + wn + ni * 16 + lo16;
        float bv = bias[col];
        #pragma unroll
        for (int mi = 0; mi < 4; ++mi) {
            int row0 = rowBase + wm + mi * 16 + quad * 4;
            #pragma unroll
            for (int r = 0; r < 4; ++r)
                qkv[(size_t)(row0 + r) * N_QKV + col] = (bf16)((acc[mi][ni][r] + bv) * scale);
        }
    }
}

// ---------------- flash attention v14: v11 structure + forced 2-blocks/CU occupancy ----------------
// Diagnosis: OccupancyPercent 18-21% across v8/v10/v11 => only ONE 512-thread block
// resident per CU (8 waves, 2/SIMD). Reported VGPR_Count (92) excludes MFMA acc regs;
// unified VGPR+AGPR footprint ~155 under launch_bounds(512,2)'s 256-reg budget.
// Fix: __launch_bounds__(512,4) caps the unified budget at 128/wave -> 2 blocks/CU.
// To fit 128: drop the o_l ones-MFMA (16 acc regs), restore v8's proven VALU l_acc +
// shuffle epilogue (4 regs). Fragment paths identical to v11 (passed, absmax 0.0015).
#define NKT (T_DIM / 128)

#define FLASH_IT(KT, VC, VN)                                                          \
    {                                                                                 \
        bf16x8 nkf0 = kf0, nkf1 = kf1;                                                \
        if ((KT) + 1 < NKT) {                                                         \
            const bf16* kp = kfb + (size_t)((KT) + 1) * 128 * N_QKV;                  \
            nkf0 = *(const bf16x8*)(kp);                                              \
            nkf1 = *(const bf16x8*)(kp + 32);                                         \
            const bf16* vp = vfb + (size_t)((KT) + 1) * 128 * N_QKV;                  \
            _Pragma("unroll")                                                         \
            for (int mi = 0; mi < 4; ++mi)                                            \
                _Pragma("unroll")                                                     \
                for (int i = 0; i < 4; ++i)                                           \
                    VN[mi][i] = vp[(size_t)i * N_QKV + mi * 16];                      \
        }                                                                             \
        f32x4 st[4];                                                                  \
        __builtin_amdgcn_s_setprio(1);                                                \
        _Pragma("unroll")                                                             \
        for (int nq = 0; nq < 4; ++nq) {                                              \
            f32x4 z = {};                                                             \
            z = __builtin_amdgcn_mfma_f32_16x16x32_bf16(kf0, qf[nq][0], z, 0, 0, 0);  \
            st[nq] = __builtin_amdgcn_mfma_f32_16x16x32_bf16(kf1, qf[nq][1], z, 0, 0, 0); \
        }                                                                             \
        __builtin_amdgcn_s_setprio(0);                                                \
        bf16x4 pb[4];                                                                 \
        _Pragma("unroll")                                                             \
        for (int nq = 0; nq < 4; ++nq)                                                \
            _Pragma("unroll")                                                         \
            for (int r = 0; r < 4; ++r) {                                             \
                float p = __builtin_amdgcn_exp2f(st[nq][r]);                          \
                l_acc[nq] += p;                                                       \
                pb[nq][r] = (bf16)p;                                                  \
            }                                                                         \
        __builtin_amdgcn_s_setprio(1);                                                \
        _Pragma("unroll")                                                             \
        for (int nq = 0; nq < 4; ++nq)                                                \
            _Pragma("unroll")                                                         \
            for (int mi = 0; mi < 4; ++mi)                                            \
                o_t[nq][mi] = mfma16(pb[nq], VC[mi], o_t[nq][mi]);                    \
        __builtin_amdgcn_s_setprio(0);                                                \
        kf0 = nkf0; kf1 = nkf1;                                                       \
    }

__global__ __launch_bounds__(512, 4) void flash_kernel(
    const bf16* __restrict__ qkv,    // [T][3C]
    bf16* __restrict__ y)            // [T][C]
{
    __shared__ float Ored[8][16][67];   // [wave][q_local][d] (+pad)
    __shared__ float lred[8][64];

    const int bid = blockIdx.x;
    const int xcd = bid & 7, slot = bid >> 3;   // slot 0..63
    const int h = xcd * 2 + (slot & 1);
    const int qb = slot >> 1;                   // 0..31
    const int tid  = threadIdx.x;
    const int lane = tid & 63, w = tid >> 6;    // w in 0..7
    const int lo16 = lane & 15, quad = lane >> 4;

    bf16x8 qf[4][2];
    #pragma unroll
    for (int nq = 0; nq < 4; ++nq)
        #pragma unroll
        for (int dk = 0; dk < 2; ++dk)
            qf[nq][dk] = *(const bf16x8*)(qkv + (size_t)(qb * 64 + nq * 16 + lo16) * N_QKV
                                          + h * D_HEAD + dk * 32 + quad * 8);

    f32x4 o_t[4][4] = {};   // [nq][mi]: O[q = nq*16+quad*4+i][d = mi*16+lo16]
    float l_acc[4] = {};    // partial l for q = nq*16+lo16 (over this lane's keys)

    // K fragment base: K[s = w*16+lo16][d = quad*8..]
    const bf16* kfb = qkv + (size_t)(w * 16 + lo16) * N_QKV + C_DIM + h * D_HEAD + quad * 8;
    // V fragment base: V[s = w*16+quad*4 + i][d = lo16 + mi*16]
    const bf16* vfb = qkv + (size_t)(w * 16 + quad * 4) * N_QKV + 2 * C_DIM + h * D_HEAD + lo16;

    bf16x8 kf0 = *(const bf16x8*)(kfb);
    bf16x8 kf1 = *(const bf16x8*)(kfb + 32);
    bf16x4 vA[4], vB[4];
    #pragma unroll
    for (int mi = 0; mi < 4; ++mi)
        #pragma unroll
        for (int i = 0; i < 4; ++i)
            vA[mi][i] = vfb[(size_t)i * N_QKV + mi * 16];

    for (int kt = 0; kt < NKT; kt += 2) {
        FLASH_IT(kt,     vA, vB);
        FLASH_IT(kt + 1, vB, vA);
    }

    // l: reduce over quad (shfl 16,32), store per-wave partial
    #pragma unroll
    for (int nq = 0; nq < 4; ++nq) {
        l_acc[nq] += __shfl_xor(l_acc[nq], 16);
        l_acc[nq] += __shfl_xor(l_acc[nq], 32);
        if (quad == 0) lred[w][nq * 16 + lo16] = l_acc[nq];
    }

    const int qloc = tid >> 5;          // 0..15
    const int d0   = (tid & 31) * 2;    // 0,2,..,62
    for (int nq = 0; nq < 4; ++nq) {
        __syncthreads();
        #pragma unroll
        for (int mi = 0; mi < 4; ++mi)
            #pragma unroll
            for (int i = 0; i < 4; ++i)
                Ored[w][quad * 4 + i][mi * 16 + lo16] = o_t[nq][mi][i];
        __syncthreads();
        float ls = 0.f;
        #pragma unroll
        for (int j = 0; j < 8; ++j) ls += lred[j][nq * 16 + qloc];
        float linv = 1.0f / ls;
        float s0 = 0.f, s1 = 0.f;
        #pragma unroll
        for (int j = 0; j < 8; ++j) { s0 += Ored[j][qloc][d0]; s1 += Ored[j][qloc][d0 + 1]; }
        bf16x2 ov;
        ov[0] = (bf16)(s0 * linv); ov[1] = (bf16)(s1 * linv);
        *(bf16x2*)&y[(size_t)(qb * 64 + nq * 16 + qloc) * C_DIM + h * D_HEAD + d0] = ov;
    }
}

// ---------------- proj GEMM 64x64, BK=64, 2-phase DMA pipeline ----------------
#define PROJ_STAGE(BUF, K0) do {                                             \
    lds_load16(ga + (K0),      &As[BUF][0][(w * 16) * 32]);                  \
    lds_load16(ga + (K0) + 32, &As[BUF][1][(w * 16) * 32]);                  \
    lds_load16(gb + (K0),      &Bs[BUF][0][(w * 16) * 32]);                  \
    lds_load16(gb + (K0) + 32, &Bs[BUF][1][(w * 16) * 32]);                  \
} while (0)

#define PROJ_COMPUTE(BUF) do {                                               \
    _Pragma("unroll")                                                        \
    for (int p = 0; p < 2; ++p) {                                            \
        bf16x8 af[2], bfr[2];                                                \
        _Pragma("unroll")                                                    \
        for (int mi = 0; mi < 2; ++mi) af[mi]  = *(const bf16x8*)&As[BUF][p][(wm + mi * 16 + lo16) * 32 + quad * 8]; \
        _Pragma("unroll")                                                    \
        for (int ni = 0; ni < 2; ++ni) bfr[ni] = *(const bf16x8*)&Bs[BUF][p][(wn + ni * 16 + lo16) * 32 + quad * 8]; \
        _Pragma("unroll")                                                    \
        for (int mi = 0; mi < 2; ++mi)                                       \
            _Pragma("unroll")                                                \
            for (int ni = 0; ni < 2; ++ni)                                   \
                acc[mi][ni] = __builtin_amdgcn_mfma_f32_16x16x32_bf16(af[mi], bfr[ni], acc[mi][ni], 0, 0, 0); \
    }                                                                        \
} while (0)

__global__ __launch_bounds__(256, 4) void proj_gemm_kernel(
    const bf16* __restrict__ A, const bf16* __restrict__ Bt,
    const float* __restrict__ bias, float* __restrict__ out)
{
    __shared__ __align__(16) bf16 As[2][2][64 * 32];
    __shared__ __align__(16) bf16 Bs[2][2][64 * 32];
    const int bid = blockIdx.x;
    const int xcd = bid & 7, slot = bid >> 3;            // slot 0..63
    const int colBase = (xcd * 2 + (slot & 1)) * 64;
    const int rowBase = (slot >> 1) * 64;
    const int tid = threadIdx.x, lane = tid & 63, w = tid >> 6;
    const int lo16 = lane & 15, quad = lane >> 4;
    const int wm = (w & 1) * 32, wn = (w >> 1) * 32;

    const bf16* ga = A  + (size_t)(rowBase + w * 16 + (lane >> 2)) * C_DIM + (lane & 3) * 8;
    const bf16* gb = Bt + (size_t)(colBase + w * 16 + (lane >> 2)) * C_DIM + (lane & 3) * 8;

    f32x4 acc[2][2] = {};

    PROJ_STAGE(0, 0);
    WAIT_AND_BARRIER();

    for (int k0 = 0; k0 < C_DIM; k0 += 128) {
        PROJ_STAGE(1, k0 + 64);
        PROJ_COMPUTE(0);
        WAIT_AND_BARRIER();
        if (k0 + 128 < C_DIM) PROJ_STAGE(0, k0 + 128);
        PROJ_COMPUTE(1);
        WAIT_AND_BARRIER();
    }

    #pragma unroll
    for (int ni = 0; ni < 2; ++ni) {
        int col = colBase + wn + ni * 16 + lo16;
        float bv = bias[col];
        #pragma unroll
        for (int mi = 0; mi < 2; ++mi) {
            int row0 = rowBase + wm + mi * 16 + quad * 4;
            #pragma unroll
            for (int r = 0; r < 4; ++r)
                out[(size_t)(row0 + r) * C_DIM + col] = acc[mi][ni][r] + bv;
        }
    }
}

extern "C" void kernel_launch(void* const* d_in, const int* in_sizes, int n_in,
                              void* d_out, int out_size, void* d_ws, size_t ws_size,
                              hipStream_t stream) {
    const float* x      = (const float*)d_in[0];
    const float* W_qkv  = (const float*)d_in[1];
    const float* b_qkv  = (const float*)d_in[2];
    const float* W_proj = (const float*)d_in[3];
    const float* b_proj = (const float*)d_in[4];
    float* out = (float*)d_out;

    char* ws = (char*)d_ws;
    bf16* xb      = (bf16*)(ws);                 // [0,4) MB
    bf16* Wqkv_t  = (bf16*)(ws + (4  << 20));    // [4,10) MB
    bf16* Wproj_t = (bf16*)(ws + (10 << 20));    // [10,12) MB
    bf16* qkv_bf  = (bf16*)(ws + (12 << 20));    // [12,24) MB  interleaved [T][3072], Q prescaled
    bf16* yb      = (bf16*)(ws + (24 << 20));    // [24,28) MB

    prep_kernel<<<5120, 256, 0, stream>>>(x, xb, W_qkv, Wqkv_t, W_proj, Wqkv_t == nullptr ? nullptr : Wproj_t);

    qkv_gemm_kernel<<<384, 256, 0, stream>>>(xb, Wqkv_t, b_qkv, qkv_bf);

    flash_kernel<<<512, 512, 0, stream>>>(qkv_bf, yb);

    proj_gemm_kernel<<<512, 256, 0, stream>>>(yb, Wproj_t, b_proj, out);
}

// Round 8
// 155.216 us; speedup vs baseline: 2.1233x; 2.1233x over previous
//
#include <hip/hip_runtime.h>
#include <hip/hip_bf16.h>
#include <stdint.h>

#define T_DIM 2048
#define C_DIM 1024
#define H_DIM 16
#define D_HEAD 64
#define N_QKV 3072
#define CQ 0.18033688011112042f   // log2(e)/8

typedef __bf16 bf16;
typedef __bf16 bf16x8 __attribute__((ext_vector_type(8)));
typedef __bf16 bf16x4 __attribute__((ext_vector_type(4)));
typedef __bf16 bf16x2 __attribute__((ext_vector_type(2)));
typedef float f32x4 __attribute__((ext_vector_type(4)));
typedef short s16x4 __attribute__((ext_vector_type(4)));

__device__ __forceinline__ void lds_load16(const void* g, void* l) {
    __builtin_amdgcn_global_load_lds(
        (const __attribute__((address_space(1))) void*)g,
        (__attribute__((address_space(3))) void*)l, 16, 0, 0);
}

__device__ __forceinline__ f32x4 mfma16(bf16x4 a, bf16x4 b, f32x4 c) {
#if __has_builtin(__builtin_amdgcn_mfma_f32_16x16x16_bf16)
    return __builtin_amdgcn_mfma_f32_16x16x16_bf16(a, b, c, 0, 0, 0);
#elif __has_builtin(__builtin_amdgcn_mfma_f32_16x16x16bf16_1k)
    union { bf16x4 v; s16x4 s; } ua, ub;
    ua.v = a; ub.v = b;
    return __builtin_amdgcn_mfma_f32_16x16x16bf16_1k(ua.s, ub.s, c, 0, 0, 0);
#else
    asm volatile("v_mfma_f32_16x16x16_bf16 %0, %1, %2, %0"
                 : "+v"(c) : "v"(a), "v"(b));
    return c;
#endif
}

// ---- merged prep: blocks 0..1023 cast x; blocks 1024..5119 transpose both weights ----
__global__ void prep_kernel(const float* __restrict__ x, bf16* __restrict__ xb,
                            const float* __restrict__ Wq, bf16* __restrict__ WqT,
                            const float* __restrict__ Wp, bf16* __restrict__ WpT) {
    __shared__ float tile[32][33];
    int bid = blockIdx.x;
    int t = threadIdx.x;
    if (bid < 1024) {
        int i = (bid * 256 + t) * 8;
        float4 a = *(const float4*)(x + i);
        float4 b = *(const float4*)(x + i + 4);
        bf16x8 o;
        o[0] = (bf16)a.x; o[1] = (bf16)a.y; o[2] = (bf16)a.z; o[3] = (bf16)a.w;
        o[4] = (bf16)b.x; o[5] = (bf16)b.y; o[6] = (bf16)b.z; o[7] = (bf16)b.w;
        *(bf16x8*)(xb + i) = o;
        return;
    }
    bid -= 1024;
    const float* in; bf16* out; int N, nb, kb;
    if (bid < 3072) { in = Wq; out = WqT; N = N_QKV; nb = (bid % 96) * 32; kb = (bid / 96) * 32; }
    else { bid -= 3072; in = Wp; out = WpT; N = C_DIM; nb = (bid % 32) * 32; kb = (bid / 32) * 32; }
    int r = t >> 3, c4 = (t & 7) * 4;
    float4 v = *(const float4*)(in + (size_t)(kb + r) * N + nb + c4);
    tile[r][c4 + 0] = v.x; tile[r][c4 + 1] = v.y;
    tile[r][c4 + 2] = v.z; tile[r][c4 + 3] = v.w;
    __syncthreads();
    bf16x4 ov;
    ov[0] = (bf16)tile[c4 + 0][r]; ov[1] = (bf16)tile[c4 + 1][r];
    ov[2] = (bf16)tile[c4 + 2][r]; ov[3] = (bf16)tile[c4 + 3][r];
    *(bf16x4*)(out + (size_t)(nb + r) * C_DIM + kb + c4) = ov;
}

// ---------------- QKV GEMM 128x128, BK=64, 2-phase DMA pipeline, XCD-swizzled ----------------
#define QKV_STAGE(BUF, K0) do {                                                      \
    lds_load16(ga + (K0),                            &As[BUF][0][(w * 16) * 32]);    \
    lds_load16(ga + (K0) + 32,                       &As[BUF][1][(w * 16) * 32]);    \
    lds_load16(ga + (size_t)64 * C_DIM + (K0),       &As[BUF][0][(64 + w * 16) * 32]); \
    lds_load16(ga + (size_t)64 * C_DIM + (K0) + 32,  &As[BUF][1][(64 + w * 16) * 32]); \
    lds_load16(gb + (K0),                            &Bs[BUF][0][(w * 16) * 32]);    \
    lds_load16(gb + (K0) + 32,                       &Bs[BUF][1][(w * 16) * 32]);    \
    lds_load16(gb + (size_t)64 * C_DIM + (K0),       &Bs[BUF][0][(64 + w * 16) * 32]); \
    lds_load16(gb + (size_t)64 * C_DIM + (K0) + 32,  &Bs[BUF][1][(64 + w * 16) * 32]); \
} while (0)

#define QKV_COMPUTE(BUF) do {                                                \
    _Pragma("unroll")                                                        \
    for (int p = 0; p < 2; ++p) {                                            \
        bf16x8 af[4], bfr[4];                                                \
        _Pragma("unroll")                                                    \
        for (int mi = 0; mi < 4; ++mi) af[mi]  = *(const bf16x8*)&As[BUF][p][(wm + mi * 16 + lo16) * 32 + quad * 8]; \
        _Pragma("unroll")                                                    \
        for (int ni = 0; ni < 4; ++ni) bfr[ni] = *(const bf16x8*)&Bs[BUF][p][(wn + ni * 16 + lo16) * 32 + quad * 8]; \
        _Pragma("unroll")                                                    \
        for (int mi = 0; mi < 4; ++mi)                                       \
            _Pragma("unroll")                                                \
            for (int ni = 0; ni < 4; ++ni)                                   \
                acc[mi][ni] = __builtin_amdgcn_mfma_f32_16x16x32_bf16(af[mi], bfr[ni], acc[mi][ni], 0, 0, 0); \
    }                                                                        \
} while (0)

#define WAIT_AND_BARRIER() do {                                              \
    asm volatile("s_waitcnt vmcnt(0)" ::: "memory");                         \
    __builtin_amdgcn_s_barrier();                                            \
} while (0)

__global__ __launch_bounds__(256, 2) void qkv_gemm_kernel(
    const bf16* __restrict__ A, const bf16* __restrict__ Bt,
    const float* __restrict__ bias, bf16* __restrict__ qkv)
{
    __shared__ __align__(16) bf16 As[2][2][128 * 32];
    __shared__ __align__(16) bf16 Bs[2][2][128 * 32];
    const int bid = blockIdx.x;
    const int xcd = bid & 7, slot = bid >> 3;            // slot 0..47
    const int rowBase = (slot / 3) * 128;                // 16 row-blocks
    const int colBase = (xcd * 3 + (slot % 3)) * 128;    // 24 col-blocks
    const int tid = threadIdx.x, lane = tid & 63, w = tid >> 6;
    const int lo16 = lane & 15, quad = lane >> 4;
    const int wm = (w & 1) * 64, wn = (w >> 1) * 64;

    const bf16* ga = A  + (size_t)(rowBase + w * 16 + (lane >> 2)) * C_DIM + (lane & 3) * 8;
    const bf16* gb = Bt + (size_t)(colBase + w * 16 + (lane >> 2)) * C_DIM + (lane & 3) * 8;

    f32x4 acc[4][4] = {};

    QKV_STAGE(0, 0);
    WAIT_AND_BARRIER();

    for (int k0 = 0; k0 < C_DIM; k0 += 128) {
        QKV_STAGE(1, k0 + 64);
        QKV_COMPUTE(0);
        WAIT_AND_BARRIER();
        if (k0 + 128 < C_DIM) QKV_STAGE(0, k0 + 128);
        QKV_COMPUTE(1);
        WAIT_AND_BARRIER();
    }

    const float scale = (colBase < C_DIM) ? CQ : 1.0f;   // Q region prescale (128 | 1024)
    #pragma unroll
    for (int ni = 0; ni < 4; ++ni) {
        int col = colBase + wn + ni * 16 + lo16;
        float bv = bias[col];
        #pragma unroll
        for (int mi = 0; mi < 4; ++mi) {
            int row0 = rowBase + wm + mi * 16 + quad * 4;
            #pragma unroll
            for (int r = 0; r < 4; ++r)
                qkv[(size_t)(row0 + r) * N_QKV + col] = (bf16)((acc[mi][ni][r] + bv) * scale);
        }
    }
}

// ---------------- flash attention v16: 256-thread blocks, lean registers, LDS V tile ----------------
// r7 evidence: occupancy IS the bottleneck (42% when forced) but 64-reg accumulator state
// of the 64q-per-wave design can't fit 128 regs (spilled). Fix by RESTRUCTURING:
// 1024 blocks x 256 threads (4 waves). Block = 32 q-rows x 1 head; waves key-split 4x16
// over 64-key tiles. Per-wave state ~115 regs (o_t 32 + o_l 8 + qf 16 + kf 16 + vf 8 + temps)
// -> 3-4 blocks/CU = 12-16 waves/CU without spills (launch_bounds (256,3): 170 budget).
// V path (r4 LSU diagnosis): 2 block-wide global_load_lds DMAs stage V[64k][64d] (dbuf,
// 16KB shared by all 4 waves); frags read as 16 ds_read_u16. Bank-conflict-free via XOR
// swizzle of col bits[5:4] with row bits[3:2], applied inversely on the DMA *source*
// address (m173 pattern; involution: read-col (mi^quad)<<4|lo16 ^ swz(row)=quad<<4).
// MFMA fragment paths bit-identical to validated v10/v11 (pb-as-A PV, ones-MFMA l).
#define NKT (T_DIM / 64)

#define STAGE_V(B, KT) do {                                                  \
    const bf16* vs_ = vsrc + (size_t)(KT) * 64 * N_QKV;                      \
    lds_load16(vs_,                         &u.Vs[(B) * 4096 + w * 512]);    \
    lds_load16(vs_ + (size_t)32 * N_QKV,    &u.Vs[(B) * 4096 + 2048 + w * 512]); \
} while (0)

__global__ __launch_bounds__(256, 3) void flash_kernel(
    const bf16* __restrict__ qkv,    // [T][3C]
    bf16* __restrict__ y)            // [T][C]
{
    __shared__ union {
        __align__(16) bf16 Vs[2 * 4096];    // [buf][row=key(64)][col=d(64), swizzled]
        float Ored[4][16][68];              // [wave][q_local][d] (+pad)
    } u;
    __shared__ float lred[4][32];

    const int bid = blockIdx.x;
    const int xcd = bid & 7, slot = bid >> 3;   // slot 0..127
    const int h = xcd * 2 + (slot & 1);
    const int qb = slot >> 1;                   // 0..63 (32 q-rows each)
    const int tid  = threadIdx.x;
    const int lane = tid & 63, w = tid >> 6;    // w in 0..3
    const int lo16 = lane & 15, quad = lane >> 4;

    // Q fragments: 32 q rows -> nq=0..1
    bf16x8 qf[2][2];
    #pragma unroll
    for (int nq = 0; nq < 2; ++nq)
        #pragma unroll
        for (int dk = 0; dk < 2; ++dk)
            qf[nq][dk] = *(const bf16x8*)(qkv + (size_t)(qb * 32 + nq * 16 + lo16) * N_QKV
                                          + h * D_HEAD + dk * 32 + quad * 8);

    f32x4 o_t[2][4] = {};   // [nq][mi]: O[q = nq*16+quad*4+i][d = mi*16+lo16]
    f32x4 o_l[2] = {};      // l[q = nq*16+lo16] (replicated over r)
    bf16x4 ones1;
    ones1[0] = (bf16)1.0f; ones1[1] = (bf16)1.0f; ones1[2] = (bf16)1.0f; ones1[3] = (bf16)1.0f;

    // K fragment base: K[s = w*16+lo16 (+kt*64)][d = quad*8 (+dk*32)]
    const bf16* kfb = qkv + (size_t)(w * 16 + lo16) * N_QKV + C_DIM + h * D_HEAD + quad * 8;
    // V DMA source (inverse-swizzled): thread t, instr p covers tile row p*32+(t>>3),
    // src col = ((t&7)*8) ^ (((row>>2)&3)<<4); p*32 doesn't affect (row>>2)&3.
    const int vcol = ((tid & 7) << 3) ^ (((tid >> 5) & 3) << 4);
    const bf16* vsrc = qkv + 2 * C_DIM + h * D_HEAD + (size_t)(tid >> 3) * N_QKV + vcol;
    // V read base: row = w*16 + quad*4 (+j), col_mem = ((mi^quad)<<4) | lo16
    const int vrbase = (w * 16 + quad * 4) * 64 + lo16;

    bf16x8 kf0 = *(const bf16x8*)(kfb);
    bf16x8 kf1 = *(const bf16x8*)(kfb + 32);
    STAGE_V(0, 0);

    for (int kt = 0; kt < NKT; ++kt) {
        const int b = kt & 1;
        WAIT_AND_BARRIER();   // own DMA (buf b) + K loads landed; all waves' DMA visible

        // V fragments from staged tile (swizzled cols -> conflict-free)
        bf16x4 vf[4];
        #pragma unroll
        for (int mi = 0; mi < 4; ++mi)
            #pragma unroll
            for (int j = 0; j < 4; ++j)
                vf[mi][j] = u.Vs[b * 4096 + vrbase + j * 64 + (((mi ^ quad)) << 4)];

        // issue next tile's DMA + K prefetch (full iteration of flight)
        bf16x8 nkf0 = kf0, nkf1 = kf1;
        if (kt + 1 < NKT) {
            STAGE_V(b ^ 1, kt + 1);
            const bf16* kp = kfb + (size_t)(kt + 1) * 64 * N_QKV;
            nkf0 = *(const bf16x8*)(kp);
            nkf1 = *(const bf16x8*)(kp + 32);
        }

        f32x4 st[2];
        __builtin_amdgcn_s_setprio(1);
        #pragma unroll
        for (int nq = 0; nq < 2; ++nq) {
            f32x4 z = {};
            z = __builtin_amdgcn_mfma_f32_16x16x32_bf16(kf0, qf[nq][0], z, 0, 0, 0);
            st[nq] = __builtin_amdgcn_mfma_f32_16x16x32_bf16(kf1, qf[nq][1], z, 0, 0, 0);
        }
        __builtin_amdgcn_s_setprio(0);

        bf16x4 pb[2];
        #pragma unroll
        for (int nq = 0; nq < 2; ++nq)
            #pragma unroll
            for (int r = 0; r < 4; ++r)
                pb[nq][r] = (bf16)__builtin_amdgcn_exp2f(st[nq][r]);

        __builtin_amdgcn_s_setprio(1);
        #pragma unroll
        for (int nq = 0; nq < 2; ++nq)
            o_l[nq] = mfma16(ones1, pb[nq], o_l[nq]);
        #pragma unroll
        for (int nq = 0; nq < 2; ++nq)
            #pragma unroll
            for (int mi = 0; mi < 4; ++mi)
                o_t[nq][mi] = mfma16(pb[nq], vf[mi], o_t[nq][mi]);
        __builtin_amdgcn_s_setprio(0);

        kf0 = nkf0; kf1 = nkf1;
    }

    // per-wave partial l (replicated over r -> single write per q)
    if (quad == 0) {
        #pragma unroll
        for (int nq = 0; nq < 2; ++nq)
            lred[w][nq * 16 + lo16] = o_l[nq][0];
    }

    const int qloc = tid >> 4;          // 0..15
    const int d0   = (tid & 15) * 4;    // 0,4,..,60
    #pragma unroll
    for (int nq = 0; nq < 2; ++nq) {
        __syncthreads();
        #pragma unroll
        for (int mi = 0; mi < 4; ++mi)
            #pragma unroll
            for (int i = 0; i < 4; ++i)
                u.Ored[w][quad * 4 + i][mi * 16 + lo16] = o_t[nq][mi][i];
        __syncthreads();
        float ls = 0.f;
        #pragma unroll
        for (int j = 0; j < 4; ++j) ls += lred[j][nq * 16 + qloc];
        float linv = 1.0f / ls;
        bf16x4 ov;
        #pragma unroll
        for (int di = 0; di < 4; ++di) {
            float s = 0.f;
            #pragma unroll
            for (int j = 0; j < 4; ++j) s += u.Ored[j][qloc][d0 + di];
            ov[di] = (bf16)(s * linv);
        }
        *(bf16x4*)&y[(size_t)(qb * 32 + nq * 16 + qloc) * C_DIM + h * D_HEAD + d0] = ov;
    }
}

// ---------------- proj GEMM 64x64, BK=64, 2-phase DMA pipeline ----------------
#define PROJ_STAGE(BUF, K0) do {                                             \
    lds_load16(ga + (K0),      &As[BUF][0][(w * 16) * 32]);                  \
    lds_load16(ga + (K0) + 32, &As[BUF][1][(w * 16) * 32]);                  \
    lds_load16(gb + (K0),      &Bs[BUF][0][(w * 16) * 32]);                  \
    lds_load16(gb + (K0) + 32, &Bs[BUF][1][(w * 16) * 32]);                  \
} while (0)

#define PROJ_COMPUTE(BUF) do {                                               \
    _Pragma("unroll")                                                        \
    for (int p = 0; p < 2; ++p) {                                            \
        bf16x8 af[2], bfr[2];                                                \
        _Pragma("unroll")                                                    \
        for (int mi = 0; mi < 2; ++mi) af[mi]  = *(const bf16x8*)&As[BUF][p][(wm + mi * 16 + lo16) * 32 + quad * 8]; \
        _Pragma("unroll")                                                    \
        for (int ni = 0; ni < 2; ++ni) bfr[ni] = *(const bf16x8*)&Bs[BUF][p][(wn + ni * 16 + lo16) * 32 + quad * 8]; \
        _Pragma("unroll")                                                    \
        for (int mi = 0; mi < 2; ++mi)                                       \
            _Pragma("unroll")                                                \
            for (int ni = 0; ni < 2; ++ni)                                   \
                acc[mi][ni] = __builtin_amdgcn_mfma_f32_16x16x32_bf16(af[mi], bfr[ni], acc[mi][ni], 0, 0, 0); \
    }                                                                        \
} while (0)

__global__ __launch_bounds__(256, 4) void proj_gemm_kernel(
    const bf16* __restrict__ A, const bf16* __restrict__ Bt,
    const float* __restrict__ bias, float* __restrict__ out)
{
    __shared__ __align__(16) bf16 As[2][2][64 * 32];
    __shared__ __align__(16) bf16 Bs[2][2][64 * 32];
    const int bid = blockIdx.x;
    const int xcd = bid & 7, slot = bid >> 3;            // slot 0..63
    const int colBase = (xcd * 2 + (slot & 1)) * 64;
    const int rowBase = (slot >> 1) * 64;
    const int tid = threadIdx.x, lane = tid & 63, w = tid >> 6;
    const int lo16 = lane & 15, quad = lane >> 4;
    const int wm = (w & 1) * 32, wn = (w >> 1) * 32;

    const bf16* ga = A  + (size_t)(rowBase + w * 16 + (lane >> 2)) * C_DIM + (lane & 3) * 8;
    const bf16* gb = Bt + (size_t)(colBase + w * 16 + (lane >> 2)) * C_DIM + (lane & 3) * 8;

    f32x4 acc[2][2] = {};

    PROJ_STAGE(0, 0);
    WAIT_AND_BARRIER();

    for (int k0 = 0; k0 < C_DIM; k0 += 128) {
        PROJ_STAGE(1, k0 + 64);
        PROJ_COMPUTE(0);
        WAIT_AND_BARRIER();
        if (k0 + 128 < C_DIM) PROJ_STAGE(0, k0 + 128);
        PROJ_COMPUTE(1);
        WAIT_AND_BARRIER();
    }

    #pragma unroll
    for (int ni = 0; ni < 2; ++ni) {
        int col = colBase + wn + ni * 16 + lo16;
        float bv = bias[col];
        #pragma unroll
        for (int mi = 0; mi < 2; ++mi) {
            int row0 = rowBase + wm + mi * 16 + quad * 4;
            #pragma unroll
            for (int r = 0; r < 4; ++r)
                out[(size_t)(row0 + r) * C_DIM + col] = acc[mi][ni][r] + bv;
        }
    }
}

extern "C" void kernel_launch(void* const* d_in, const int* in_sizes, int n_in,
                              void* d_out, int out_size, void* d_ws, size_t ws_size,
                              hipStream_t stream) {
    const float* x      = (const float*)d_in[0];
    const float* W_qkv  = (const float*)d_in[1];
    const float* b_qkv  = (const float*)d_in[2];
    const float* W_proj = (const float*)d_in[3];
    const float* b_proj = (const float*)d_in[4];
    float* out = (float*)d_out;

    char* ws = (char*)d_ws;
    bf16* xb      = (bf16*)(ws);                 // [0,4) MB
    bf16* Wqkv_t  = (bf16*)(ws + (4  << 20));    // [4,10) MB
    bf16* Wproj_t = (bf16*)(ws + (10 << 20));    // [10,12) MB
    bf16* qkv_bf  = (bf16*)(ws + (12 << 20));    // [12,24) MB  interleaved [T][3072], Q prescaled
    bf16* yb      = (bf16*)(ws + (24 << 20));    // [24,28) MB

    prep_kernel<<<5120, 256, 0, stream>>>(x, xb, W_qkv, Wqkv_t, W_proj, Wproj_t);

    qkv_gemm_kernel<<<384, 256, 0, stream>>>(xb, Wqkv_t, b_qkv, qkv_bf);

    flash_kernel<<<1024, 256, 0, stream>>>(qkv_bf, yb);

    proj_gemm_kernel<<<512, 256, 0, stream>>>(yb, Wproj_t, b_proj, out);
}

// Round 9
// 146.945 us; speedup vs baseline: 2.2429x; 1.0563x over previous
//
#include <hip/hip_runtime.h>
#include <hip/hip_bf16.h>
#include <stdint.h>

#define T_DIM 2048
#define C_DIM 1024
#define H_DIM 16
#define D_HEAD 64
#define N_QKV 3072
#define CQ 0.18033688011112042f   // log2(e)/8

typedef __bf16 bf16;
typedef __bf16 bf16x8 __attribute__((ext_vector_type(8)));
typedef __bf16 bf16x4 __attribute__((ext_vector_type(4)));
typedef __bf16 bf16x2 __attribute__((ext_vector_type(2)));
typedef float f32x4 __attribute__((ext_vector_type(4)));
typedef short s16x4 __attribute__((ext_vector_type(4)));

__device__ __forceinline__ void lds_load16(const void* g, void* l) {
    __builtin_amdgcn_global_load_lds(
        (const __attribute__((address_space(1))) void*)g,
        (__attribute__((address_space(3))) void*)l, 16, 0, 0);
}

__device__ __forceinline__ f32x4 mfma16(bf16x4 a, bf16x4 b, f32x4 c) {
#if __has_builtin(__builtin_amdgcn_mfma_f32_16x16x16_bf16)
    return __builtin_amdgcn_mfma_f32_16x16x16_bf16(a, b, c, 0, 0, 0);
#elif __has_builtin(__builtin_amdgcn_mfma_f32_16x16x16bf16_1k)
    union { bf16x4 v; s16x4 s; } ua, ub;
    ua.v = a; ub.v = b;
    return __builtin_amdgcn_mfma_f32_16x16x16bf16_1k(ua.s, ub.s, c, 0, 0, 0);
#else
    asm volatile("v_mfma_f32_16x16x16_bf16 %0, %1, %2, %0"
                 : "+v"(c) : "v"(a), "v"(b));
    return c;
#endif
}

// ---- merged prep: blocks 0..1023 cast x; blocks 1024..5119 transpose both weights ----
__global__ void prep_kernel(const float* __restrict__ x, bf16* __restrict__ xb,
                            const float* __restrict__ Wq, bf16* __restrict__ WqT,
                            const float* __restrict__ Wp, bf16* __restrict__ WpT) {
    __shared__ float tile[32][33];
    int bid = blockIdx.x;
    int t = threadIdx.x;
    if (bid < 1024) {
        int i = (bid * 256 + t) * 8;
        float4 a = *(const float4*)(x + i);
        float4 b = *(const float4*)(x + i + 4);
        bf16x8 o;
        o[0] = (bf16)a.x; o[1] = (bf16)a.y; o[2] = (bf16)a.z; o[3] = (bf16)a.w;
        o[4] = (bf16)b.x; o[5] = (bf16)b.y; o[6] = (bf16)b.z; o[7] = (bf16)b.w;
        *(bf16x8*)(xb + i) = o;
        return;
    }
    bid -= 1024;
    const float* in; bf16* out; int N, nb, kb;
    if (bid < 3072) { in = Wq; out = WqT; N = N_QKV; nb = (bid % 96) * 32; kb = (bid / 96) * 32; }
    else { bid -= 3072; in = Wp; out = WpT; N = C_DIM; nb = (bid % 32) * 32; kb = (bid / 32) * 32; }
    int r = t >> 3, c4 = (t & 7) * 4;
    float4 v = *(const float4*)(in + (size_t)(kb + r) * N + nb + c4);
    tile[r][c4 + 0] = v.x; tile[r][c4 + 1] = v.y;
    tile[r][c4 + 2] = v.z; tile[r][c4 + 3] = v.w;
    __syncthreads();
    bf16x4 ov;
    ov[0] = (bf16)tile[c4 + 0][r]; ov[1] = (bf16)tile[c4 + 1][r];
    ov[2] = (bf16)tile[c4 + 2][r]; ov[3] = (bf16)tile[c4 + 3][r];
    *(bf16x4*)(out + (size_t)(nb + r) * C_DIM + kb + c4) = ov;
}

// ---------------- QKV GEMM 128x128, BK=64, 2-phase DMA pipeline, XCD-swizzled ----------------
#define QKV_STAGE(BUF, K0) do {                                                      \
    lds_load16(ga + (K0),                            &As[BUF][0][(w * 16) * 32]);    \
    lds_load16(ga + (K0) + 32,                       &As[BUF][1][(w * 16) * 32]);    \
    lds_load16(ga + (size_t)64 * C_DIM + (K0),       &As[BUF][0][(64 + w * 16) * 32]); \
    lds_load16(ga + (size_t)64 * C_DIM + (K0) + 32,  &As[BUF][1][(64 + w * 16) * 32]); \
    lds_load16(gb + (K0),                            &Bs[BUF][0][(w * 16) * 32]);    \
    lds_load16(gb + (K0) + 32,                       &Bs[BUF][1][(w * 16) * 32]);    \
    lds_load16(gb + (size_t)64 * C_DIM + (K0),       &Bs[BUF][0][(64 + w * 16) * 32]); \
    lds_load16(gb + (size_t)64 * C_DIM + (K0) + 32,  &Bs[BUF][1][(64 + w * 16) * 32]); \
} while (0)

#define QKV_COMPUTE(BUF) do {                                                \
    _Pragma("unroll")                                                        \
    for (int p = 0; p < 2; ++p) {                                            \
        bf16x8 af[4], bfr[4];                                                \
        _Pragma("unroll")                                                    \
        for (int mi = 0; mi < 4; ++mi) af[mi]  = *(const bf16x8*)&As[BUF][p][(wm + mi * 16 + lo16) * 32 + quad * 8]; \
        _Pragma("unroll")                                                    \
        for (int ni = 0; ni < 4; ++ni) bfr[ni] = *(const bf16x8*)&Bs[BUF][p][(wn + ni * 16 + lo16) * 32 + quad * 8]; \
        _Pragma("unroll")                                                    \
        for (int mi = 0; mi < 4; ++mi)                                       \
            _Pragma("unroll")                                                \
            for (int ni = 0; ni < 4; ++ni)                                   \
                acc[mi][ni] = __builtin_amdgcn_mfma_f32_16x16x32_bf16(af[mi], bfr[ni], acc[mi][ni], 0, 0, 0); \
    }                                                                        \
} while (0)

#define WAIT_AND_BARRIER() do {                                              \
    asm volatile("s_waitcnt vmcnt(0)" ::: "memory");                         \
    __builtin_amdgcn_s_barrier();                                            \
} while (0)

__global__ __launch_bounds__(256, 2) void qkv_gemm_kernel(
    const bf16* __restrict__ A, const bf16* __restrict__ Bt,
    const float* __restrict__ bias, bf16* __restrict__ qkv)
{
    __shared__ __align__(16) bf16 As[2][2][128 * 32];
    __shared__ __align__(16) bf16 Bs[2][2][128 * 32];
    const int bid = blockIdx.x;
    const int xcd = bid & 7, slot = bid >> 3;            // slot 0..47
    const int rowBase = (slot / 3) * 128;                // 16 row-blocks
    const int colBase = (xcd * 3 + (slot % 3)) * 128;    // 24 col-blocks
    const int tid = threadIdx.x, lane = tid & 63, w = tid >> 6;
    const int lo16 = lane & 15, quad = lane >> 4;
    const int wm = (w & 1) * 64, wn = (w >> 1) * 64;

    const bf16* ga = A  + (size_t)(rowBase + w * 16 + (lane >> 2)) * C_DIM + (lane & 3) * 8;
    const bf16* gb = Bt + (size_t)(colBase + w * 16 + (lane >> 2)) * C_DIM + (lane & 3) * 8;

    f32x4 acc[4][4] = {};

    QKV_STAGE(0, 0);
    WAIT_AND_BARRIER();

    for (int k0 = 0; k0 < C_DIM; k0 += 128) {
        QKV_STAGE(1, k0 + 64);
        QKV_COMPUTE(0);
        WAIT_AND_BARRIER();
        if (k0 + 128 < C_DIM) QKV_STAGE(0, k0 + 128);
        QKV_COMPUTE(1);
        WAIT_AND_BARRIER();
    }

    const float scale = (colBase < C_DIM) ? CQ : 1.0f;   // Q region prescale (128 | 1024)
    #pragma unroll
    for (int ni = 0; ni < 4; ++ni) {
        int col = colBase + wn + ni * 16 + lo16;
        float bv = bias[col];
        #pragma unroll
        for (int mi = 0; mi < 4; ++mi) {
            int row0 = rowBase + wm + mi * 16 + quad * 4;
            #pragma unroll
            for (int r = 0; r < 4; ++r)
                qkv[(size_t)(row0 + r) * N_QKV + col] = (bf16)((acc[mi][ni][r] + bv) * scale);
        }
    }
}

// ---------------- flash attention v17: v8 dataflow + cross-iteration PV pipeline (T15) ----------------
// Diagnosis (r4/r7/r8 falsified VMEM-issue, occupancy, LDS-turnaround): the invariant
// 41-50us band across ALL variants is the in-wave dependency stall QK->exp->PV: PV(k)
// depends on exp(k)'s 16 trans results, so every iteration the MFMA pipe waits on the
// trans pipe (2 waves/SIMD can't cover it). Fix: shift PV one iteration. At iter k:
//   QK(k) -> PV(k-1) [uses pb,vf carried from iter k-1; independent of exp(k)] -> exp(k).
// Every producer->consumer edge now has >=1 full iteration of slack (exp->PV, vf->PV,
// K/V prefetch->use). Pure program reorder of the proven v8 math (+16 carry VGPRs).
__global__ __launch_bounds__(512, 2) void flash_kernel(
    const bf16* __restrict__ qkv,    // [T][3C]
    bf16* __restrict__ y)            // [T][C]
{
    __shared__ union {
        __align__(16) bf16 Vt[4][64][38];       // [w>>1][d][(w&1)*16 + s']
        float Ored[8][16][66];                  // [wave][d_local][q]
    } u;
    __shared__ float lred[8][64];

    const int bid = blockIdx.x;
    const int xcd = bid & 7, slot = bid >> 3;   // slot 0..63
    const int h = xcd * 2 + (slot & 1);
    const int qb = slot >> 1;                   // 0..31
    const int tid  = threadIdx.x;
    const int lane = tid & 63, w = tid >> 6;    // w in 0..7
    const int lo16 = lane & 15, quad = lane >> 4;

    bf16x8 qf[4][2];
    #pragma unroll
    for (int nq = 0; nq < 4; ++nq)
        #pragma unroll
        for (int dk = 0; dk < 2; ++dk)
            qf[nq][dk] = *(const bf16x8*)(qkv + (size_t)(qb * 64 + nq * 16 + lo16) * N_QKV
                                          + h * D_HEAD + dk * 32 + quad * 8);

    f32x4 o_t[4][4] = {};   // [mi][nq]
    float l_acc[4] = {};

    const bf16* kfb = qkv + (size_t)(w * 16 + lo16) * N_QKV + C_DIM + h * D_HEAD + quad * 8;
    const unsigned short* vb16 = (const unsigned short*)(qkv + 2 * C_DIM + h * D_HEAD);

    bf16x8 kf0 = *(const bf16x8*)(kfb);
    bf16x8 kf1 = *(const bf16x8*)(kfb + 32);
    unsigned short vreg[16];
    #pragma unroll
    for (int i = 0; i < 16; ++i)
        vreg[i] = vb16[(size_t)(w * 16 + i) * N_QKV + lane];

    bf16* vdst = &u.Vt[w >> 1][lane][(w & 1) * 16];

    bf16x4 pbp[4];   // pb carried from previous iteration
    bf16x4 vfp[4];   // vf carried from previous iteration

    // ---- iteration 0 (no PV yet) ----
    {
        union { bf16x8 v; unsigned short us[8]; } p0, p1;
        #pragma unroll
        for (int i = 0; i < 8; ++i) { p0.us[i] = vreg[i]; p1.us[i] = vreg[8 + i]; }
        *(bf16x8*)vdst       = p0.v;
        *(bf16x8*)(vdst + 8) = p1.v;

        #pragma unroll
        for (int mi = 0; mi < 4; ++mi)
            vfp[mi] = *(const bf16x4*)&u.Vt[w >> 1][mi * 16 + lo16][(w & 1) * 16 + quad * 4];

        bf16x8 nkf0 = kf0, nkf1 = kf1;
        {
            const bf16* kp = kfb + (size_t)128 * N_QKV;
            nkf0 = *(const bf16x8*)(kp);
            nkf1 = *(const bf16x8*)(kp + 32);
            #pragma unroll
            for (int i = 0; i < 16; ++i)
                vreg[i] = vb16[(size_t)(128 + w * 16 + i) * N_QKV + lane];
        }

        f32x4 st[4];
        __builtin_amdgcn_s_setprio(1);
        #pragma unroll
        for (int nq = 0; nq < 4; ++nq) {
            f32x4 z = {};
            z = __builtin_amdgcn_mfma_f32_16x16x32_bf16(kf0, qf[nq][0], z, 0, 0, 0);
            st[nq] = __builtin_amdgcn_mfma_f32_16x16x32_bf16(kf1, qf[nq][1], z, 0, 0, 0);
        }
        __builtin_amdgcn_s_setprio(0);

        #pragma unroll
        for (int nq = 0; nq < 4; ++nq)
            #pragma unroll
            for (int r = 0; r < 4; ++r) {
                float p = __builtin_amdgcn_exp2f(st[nq][r]);
                l_acc[nq] += p;
                pbp[nq][r] = (bf16)p;
            }
        kf0 = nkf0; kf1 = nkf1;
    }

    // ---- steady state: QK(kt) -> PV(kt-1) -> exp(kt) ----
    for (int kt = 1; kt < T_DIM / 128; ++kt) {
        union { bf16x8 v; unsigned short us[8]; } p0, p1;
        #pragma unroll
        for (int i = 0; i < 8; ++i) { p0.us[i] = vreg[i]; p1.us[i] = vreg[8 + i]; }
        *(bf16x8*)vdst       = p0.v;
        *(bf16x8*)(vdst + 8) = p1.v;

        // vf(kt): read now, consumed NEXT iteration (one full iter of lgkm slack)
        bf16x4 vfc[4];
        #pragma unroll
        for (int mi = 0; mi < 4; ++mi)
            vfc[mi] = *(const bf16x4*)&u.Vt[w >> 1][mi * 16 + lo16][(w & 1) * 16 + quad * 4];

        bf16x8 nkf0 = kf0, nkf1 = kf1;
        if (kt + 1 < T_DIM / 128) {
            const bf16* kp = kfb + (size_t)(kt + 1) * 128 * N_QKV;
            nkf0 = *(const bf16x8*)(kp);
            nkf1 = *(const bf16x8*)(kp + 32);
            #pragma unroll
            for (int i = 0; i < 16; ++i)
                vreg[i] = vb16[(size_t)((kt + 1) * 128 + w * 16 + i) * N_QKV + lane];
        }

        f32x4 st[4];
        __builtin_amdgcn_s_setprio(1);
        #pragma unroll
        for (int nq = 0; nq < 4; ++nq) {
            f32x4 z = {};
            z = __builtin_amdgcn_mfma_f32_16x16x32_bf16(kf0, qf[nq][0], z, 0, 0, 0);
            st[nq] = __builtin_amdgcn_mfma_f32_16x16x32_bf16(kf1, qf[nq][1], z, 0, 0, 0);
        }
        // PV(kt-1): independent of st/exp -> issues immediately behind QK
        #pragma unroll
        for (int mi = 0; mi < 4; ++mi)
            #pragma unroll
            for (int nq = 0; nq < 4; ++nq)
                o_t[mi][nq] = mfma16(vfp[mi], pbp[nq], o_t[mi][nq]);
        __builtin_amdgcn_s_setprio(0);

        // exp(kt): result consumed next iteration -> never stalls this wave
        #pragma unroll
        for (int nq = 0; nq < 4; ++nq)
            #pragma unroll
            for (int r = 0; r < 4; ++r) {
                float p = __builtin_amdgcn_exp2f(st[nq][r]);
                l_acc[nq] += p;
                pbp[nq][r] = (bf16)p;
            }
        #pragma unroll
        for (int mi = 0; mi < 4; ++mi) vfp[mi] = vfc[mi];

        kf0 = nkf0; kf1 = nkf1;
    }

    // ---- epilogue: PV(last) ----
    __builtin_amdgcn_s_setprio(1);
    #pragma unroll
    for (int mi = 0; mi < 4; ++mi)
        #pragma unroll
        for (int nq = 0; nq < 4; ++nq)
            o_t[mi][nq] = mfma16(vfp[mi], pbp[nq], o_t[mi][nq]);
    __builtin_amdgcn_s_setprio(0);

    #pragma unroll
    for (int nq = 0; nq < 4; ++nq) {
        l_acc[nq] += __shfl_xor(l_acc[nq], 16);
        l_acc[nq] += __shfl_xor(l_acc[nq], 32);
        if (quad == 0) lred[w][nq * 16 + lo16] = l_acc[nq];
    }

    const int q8 = tid >> 3, dh = tid & 7;
    float linv = 0.f;
    #pragma unroll
    for (int mi = 0; mi < 4; ++mi) {
        __syncthreads();
        #pragma unroll
        for (int nq = 0; nq < 4; ++nq)
            #pragma unroll
            for (int r = 0; r < 4; ++r)
                u.Ored[w][quad * 4 + r][nq * 16 + lo16] = o_t[mi][nq][r];
        __syncthreads();
        if (mi == 0) {
            float ls = 0.f;
            #pragma unroll
            for (int j = 0; j < 8; ++j) ls += lred[j][q8];
            linv = 1.0f / ls;
        }
        bf16x2 ov;
        #pragma unroll
        for (int dj = 0; dj < 2; ++dj) {
            int d = dh * 2 + dj;
            float s = 0.f;
            #pragma unroll
            for (int j = 0; j < 8; ++j) s += u.Ored[j][d][q8];
            ov[dj] = (bf16)(s * linv);
        }
        *(bf16x2*)&y[(size_t)(qb * 64 + q8) * C_DIM + h * D_HEAD + mi * 16 + dh * 2] = ov;
    }
}

// ---------------- proj GEMM 64x64, BK=64, 2-phase DMA pipeline ----------------
#define PROJ_STAGE(BUF, K0) do {                                             \
    lds_load16(ga + (K0),      &As[BUF][0][(w * 16) * 32]);                  \
    lds_load16(ga + (K0) + 32, &As[BUF][1][(w * 16) * 32]);                  \
    lds_load16(gb + (K0),      &Bs[BUF][0][(w * 16) * 32]);                  \
    lds_load16(gb + (K0) + 32, &Bs[BUF][1][(w * 16) * 32]);                  \
} while (0)

#define PROJ_COMPUTE(BUF) do {                                               \
    _Pragma("unroll")                                                        \
    for (int p = 0; p < 2; ++p) {                                            \
        bf16x8 af[2], bfr[2];                                                \
        _Pragma("unroll")                                                    \
        for (int mi = 0; mi < 2; ++mi) af[mi]  = *(const bf16x8*)&As[BUF][p][(wm + mi * 16 + lo16) * 32 + quad * 8]; \
        _Pragma("unroll")                                                    \
        for (int ni = 0; ni < 2; ++ni) bfr[ni] = *(const bf16x8*)&Bs[BUF][p][(wn + ni * 16 + lo16) * 32 + quad * 8]; \
        _Pragma("unroll")                                                    \
        for (int mi = 0; mi < 2; ++mi)                                       \
            _Pragma("unroll")                                                \
            for (int ni = 0; ni < 2; ++ni)                                   \
                acc[mi][ni] = __builtin_amdgcn_mfma_f32_16x16x32_bf16(af[mi], bfr[ni], acc[mi][ni], 0, 0, 0); \
    }                                                                        \
} while (0)

__global__ __launch_bounds__(256, 4) void proj_gemm_kernel(
    const bf16* __restrict__ A, const bf16* __restrict__ Bt,
    const float* __restrict__ bias, float* __restrict__ out)
{
    __shared__ __align__(16) bf16 As[2][2][64 * 32];
    __shared__ __align__(16) bf16 Bs[2][2][64 * 32];
    const int bid = blockIdx.x;
    const int xcd = bid & 7, slot = bid >> 3;            // slot 0..63
    const int colBase = (xcd * 2 + (slot & 1)) * 64;
    const int rowBase = (slot >> 1) * 64;
    const int tid = threadIdx.x, lane = tid & 63, w = tid >> 6;
    const int lo16 = lane & 15, quad = lane >> 4;
    const int wm = (w & 1) * 32, wn = (w >> 1) * 32;

    const bf16* ga = A  + (size_t)(rowBase + w * 16 + (lane >> 2)) * C_DIM + (lane & 3) * 8;
    const bf16* gb = Bt + (size_t)(colBase + w * 16 + (lane >> 2)) * C_DIM + (lane & 3) * 8;

    f32x4 acc[2][2] = {};

    PROJ_STAGE(0, 0);
    WAIT_AND_BARRIER();

    for (int k0 = 0; k0 < C_DIM; k0 += 128) {
        PROJ_STAGE(1, k0 + 64);
        PROJ_COMPUTE(0);
        WAIT_AND_BARRIER();
        if (k0 + 128 < C_DIM) PROJ_STAGE(0, k0 + 128);
        PROJ_COMPUTE(1);
        WAIT_AND_BARRIER();
    }

    #pragma unroll
    for (int ni = 0; ni < 2; ++ni) {
        int col = colBase + wn + ni * 16 + lo16;
        float bv = bias[col];
        #pragma unroll
        for (int mi = 0; mi < 2; ++mi) {
            int row0 = rowBase + wm + mi * 16 + quad * 4;
            #pragma unroll
            for (int r = 0; r < 4; ++r)
                out[(size_t)(row0 + r) * C_DIM + col] = acc[mi][ni][r] + bv;
        }
    }
}

extern "C" void kernel_launch(void* const* d_in, const int* in_sizes, int n_in,
                              void* d_out, int out_size, void* d_ws, size_t ws_size,
                              hipStream_t stream) {
    const float* x      = (const float*)d_in[0];
    const float* W_qkv  = (const float*)d_in[1];
    const float* b_qkv  = (const float*)d_in[2];
    const float* W_proj = (const float*)d_in[3];
    const float* b_proj = (const float*)d_in[4];
    float* out = (float*)d_out;

    char* ws = (char*)d_ws;
    bf16* xb      = (bf16*)(ws);                 // [0,4) MB
    bf16* Wqkv_t  = (bf16*)(ws + (4  << 20));    // [4,10) MB
    bf16* Wproj_t = (bf16*)(ws + (10 << 20));    // [10,12) MB
    bf16* qkv_bf  = (bf16*)(ws + (12 << 20));    // [12,24) MB  interleaved [T][3072], Q prescaled
    bf16* yb      = (bf16*)(ws + (24 << 20));    // [24,28) MB

    prep_kernel<<<5120, 256, 0, stream>>>(x, xb, W_qkv, Wqkv_t, W_proj, Wproj_t);

    qkv_gemm_kernel<<<384, 256, 0, stream>>>(xb, Wqkv_t, b_qkv, qkv_bf);

    flash_kernel<<<512, 512, 0, stream>>>(qkv_bf, yb);

    proj_gemm_kernel<<<512, 256, 0, stream>>>(yb, Wproj_t, b_proj, out);
}